// Round 8
// baseline (116.165 us; speedup 1.0000x reference)
//
#include <hip/hip_runtime.h>

#define S_LEN   2048
#define BATCH   32
#define NF      1024
#define CTX     20
#define KW      21            // taps
#define T_OUT   128           // output t-steps per tile = rows staged per stage
#define F_TILE  32            // features per block
#define R_PER_T 4
#define T_WIN   (R_PER_T + CTX)    // 24 sliding-window rows per thread
#define N_TILES (S_LEN / T_OUT)    // 16
#define STAGE_FLOATS 4096          // 128 rows x 32 floats = 16384 B per stage

#define WAITV(n) asm volatile("s_waitcnt vmcnt(" #n ")" ::: "memory")

typedef float f32x4_t __attribute__((ext_vector_type(4)));

// Stage one 128-row slab (16 chunks x 8 rows x 128B) into LDS, linear both sides.
// chunk c, lane l -> LDS byte (oDst*4 + c*1024 + l*16); global row = c*8+(l>>3),
// f4 = l&7. 8 consecutive lanes cover one full 128B row -> all 32 banks (no swizzle).
__device__ __forceinline__ void stage_slab(const float* __restrict__ x,
                                           float* ring, int oDst, int t0_s, int b,
                                           int f0, int wv_id, int rsub, int f4l) {
    #pragma unroll
    for (int j = 0; j < 4; ++j) {
        int chunk = j * 4 + wv_id;        // 0..15, wave-uniform
        int row   = chunk * 8 + rsub;     // 0..127, per-lane
        int t     = t0_s + row;
        t = (t < S_LEN) ? t : (S_LEN - 1);   // clamp: stage-16 junk stays in-bounds
        const float* src = x + ((size_t)t * BATCH + b) * NF + f0 + (f4l << 2);
        __builtin_amdgcn_global_load_lds(
            (const __attribute__((address_space(1))) void*)src,
            (__attribute__((address_space(3))) void*)(ring + oDst + chunk * 256),
            16, 0, 0);
    }
}

__global__ __launch_bounds__(256)   // no min-waves arg (R2 lesson: cap -> spill)
void lookahead_dwconv_kernel(const float* __restrict__ x,
                             const float* __restrict__ w,
                             float* __restrict__ out) {
    __shared__ float ring[3 * STAGE_FLOATS];   // 49152 B -> 3 blocks/CU

    const int tid    = threadIdx.x;
    const int f_tile = blockIdx.x;   // 0..31
    const int b      = blockIdx.y;   // 0..31
    const int f0     = f_tile * F_TILE;

    const int wv_id = tid >> 6;          // wave id 0..3
    const int lane  = tid & 63;
    const int rsub  = lane >> 3;         // row within 8-row chunk (0..7)
    const int f4l   = lane & 7;          // f4 slot for staging

    // compute-phase mapping
    const int f4    = tid & 7;           // float4 slot of features
    const int tg    = tid >> 3;          // 0..31
    const int tbase = tg * R_PER_T;      // 0..124

    // ---- weights -> registers, once per block (amortized 16 tiles) ----
    float wv[4][KW];
    {
        const float* wp = w + (size_t)(f0 + f4 * 4) * KW;
        #pragma unroll
        for (int c = 0; c < 4; ++c)
            #pragma unroll
            for (int k = 0; k < KW; ++k)
                wv[c][k] = wp[c * KW + k];
    }

    // ---- prologue: stage slabs 0 and 1 ----
    stage_slab(x, ring, 0,            0,     b, f0, wv_id, rsub, f4l);
    stage_slab(x, ring, STAGE_FLOATS, T_OUT, b, f0, wv_id, rsub, f4l);

    // rotating integer offsets: oA = stage t, oB = stage t+1, oC = dest for t+2
    int oA = 0, oB = STAGE_FLOATS, oC = 2 * STAGE_FLOATS;

    #pragma unroll 1
    for (int t_tile = 0; t_tile < N_TILES; ++t_tile) {
        const int t0 = t_tile * T_OUT;

        // 1. prefetch stage t+2 into oC (slab freed by the barrier of iter t-1)
        if (t_tile < N_TILES - 1)   // t=14 stages pseudo-slab 16 (clamped rows)
            stage_slab(x, ring, oC, t0 + 2 * T_OUT, b, f0, wv_id, rsub, f4l);

        // 2. counted wait: compute t needs stage t (drained 2 iters ago) AND
        //    stage t+1 (this wave's oldest 4 in queue). Per-wave queue old->new:
        //    t==0:    [s0:4][s1:4][s2:4]              -> vmcnt(4)
        //    1..14:   [s(t+1):4][stores(t-1):4][s(t+2):4] -> vmcnt(8)
        //    t==15:   [s16:4][stores14:4]             -> vmcnt(4)
        if (t_tile == 0)                 WAITV(4);
        else if (t_tile < N_TILES - 1)   WAITV(8);
        else                             WAITV(4);
        __builtin_amdgcn_s_barrier();

        // 3. compute: rows 0..127 from oA, rows 128..147 from head of oB
        float4 acc[R_PER_T];
        #pragma unroll
        for (int r = 0; r < R_PER_T; ++r)
            acc[r] = make_float4(0.f, 0.f, 0.f, 0.f);

        if (t_tile < N_TILES - 1) {
            #pragma unroll
            for (int s = 0; s < T_WIN; ++s) {
                const int row = tbase + s;
                const int off = (row < T_OUT ? oA : oB - T_OUT * F_TILE)
                                + row * F_TILE + (f4 << 2);
                float4 xv = *reinterpret_cast<const float4*>(&ring[off]);
                #pragma unroll
                for (int r = 0; r < R_PER_T; ++r) {
                    const int k = s - r;
                    if (k >= 0 && k < KW) {
                        acc[r].x = fmaf(xv.x, wv[0][k], acc[r].x);
                        acc[r].y = fmaf(xv.y, wv[1][k], acc[r].y);
                        acc[r].z = fmaf(xv.z, wv[2][k], acc[r].z);
                        acc[r].w = fmaf(xv.w, wv[3][k], acc[r].w);
                    }
                }
            }
        } else {
            // boundary tile: rows past S_LEN (== all oB-head reads here) are zeroed
            #pragma unroll
            for (int s = 0; s < T_WIN; ++s) {
                const int row = tbase + s;
                const int off = (row < T_OUT ? oA : oB - T_OUT * F_TILE)
                                + row * F_TILE + (f4 << 2);
                float4 xv = *reinterpret_cast<const float4*>(&ring[off]);
                if (t0 + row >= S_LEN) xv = make_float4(0.f, 0.f, 0.f, 0.f);
                #pragma unroll
                for (int r = 0; r < R_PER_T; ++r) {
                    const int k = s - r;
                    if (k >= 0 && k < KW) {
                        acc[r].x = fmaf(xv.x, wv[0][k], acc[r].x);
                        acc[r].y = fmaf(xv.y, wv[1][k], acc[r].y);
                        acc[r].z = fmaf(xv.z, wv[2][k], acc[r].z);
                        acc[r].w = fmaf(xv.w, wv[3][k], acc[r].w);
                    }
                }
            }
        }

        // 4. all waves done reading oA/oB-head -> next iter may overwrite old oA
        __builtin_amdgcn_s_barrier();

        // 5. stores (global, don't touch LDS)
        size_t obase = ((size_t)(t0 + tbase) * BATCH + b) * NF + f0 + (f4 << 2);
        #pragma unroll
        for (int r = 0; r < R_PER_T; ++r) {
            f32x4_t v = { acc[r].x, acc[r].y, acc[r].z, acc[r].w };
            __builtin_nontemporal_store(v,
                reinterpret_cast<f32x4_t*>(&out[obase + (size_t)r * BATCH * NF]));
        }

        // 6. rotate: A <- B <- C <- A
        int tmp = oA; oA = oB; oB = oC; oC = tmp;
    }
}

extern "C" void kernel_launch(void* const* d_in, const int* in_sizes, int n_in,
                              void* d_out, int out_size, void* d_ws, size_t ws_size,
                              hipStream_t stream) {
    const float* x = (const float*)d_in[0];
    const float* w = (const float*)d_in[1];
    float* out     = (float*)d_out;

    dim3 grid(NF / F_TILE, BATCH);   // (32, 32) = 1024 blocks, 3/CU resident
    dim3 block(256);
    lookahead_dwconv_kernel<<<grid, block, 0, stream>>>(x, w, out);
}

// Round 9
// 91.731 us; speedup vs baseline: 1.2664x; 1.2664x over previous
//
#include <hip/hip_runtime.h>

#define S_LEN   2048
#define BATCH   32
#define NF      1024
#define CTX     20
#define KW      21            // taps
#define T_OUT   128           // output t-steps per tile = rows staged per slab
#define F_TILE  32            // features per block
#define R_PER_T 4
#define T_WIN   (R_PER_T + CTX)    // 24 sliding-window rows per thread
#define N_TILES (S_LEN / T_OUT)    // 16
#define STAGE_V4 1024              // 128 rows x 8 float4 = 16384 B per slab

#define WAITV(n) asm volatile("s_waitcnt vmcnt(" #n ")" ::: "memory")

typedef float f32x4_t __attribute__((ext_vector_type(4)));

// Stage one 128-row slab (16 chunks x 8 rows x 128B) into LDS, linear both sides.
// chunk c, lane l -> LDS float4-slot (oDst + c*64 + l); global row = c*8+(l>>3),
// f4 = l&7. 8 consecutive lanes cover one full 128B row (all 32 banks).
__device__ __forceinline__ void stage_slab(const float* __restrict__ x,
                                           f32x4_t* ring, int oDst, int t0_s, int b,
                                           int f0, int wv_id, int rsub, int f4l) {
    #pragma unroll
    for (int j = 0; j < 4; ++j) {
        int chunk = j * 4 + wv_id;        // 0..15, wave-uniform
        int row   = chunk * 8 + rsub;     // 0..127, per-lane
        int t     = t0_s + row;           // always < S_LEN (junk slab never staged)
        const float* src = x + ((size_t)t * BATCH + b) * NF + f0 + (f4l << 2);
        __builtin_amdgcn_global_load_lds(
            (const __attribute__((address_space(1))) void*)src,
            (__attribute__((address_space(3))) void*)(ring + oDst + chunk * 64),
            16, 0, 0);
    }
}

__global__ __launch_bounds__(256)   // no min-waves arg (R2 lesson: cap -> spill)
void lookahead_dwconv_kernel(const float* __restrict__ x,
                             const float* __restrict__ w,
                             float* __restrict__ out) {
    __shared__ f32x4_t ring4[3 * STAGE_V4];   // 49152 B -> 3 blocks/CU

    const int tid    = threadIdx.x;
    const int f_tile = blockIdx.x;   // 0..31
    const int b      = blockIdx.y;   // 0..31
    const int f0     = f_tile * F_TILE;

    const int wv_id = tid >> 6;          // wave id 0..3
    const int lane  = tid & 63;
    const int rsub  = lane >> 3;         // row within 8-row chunk (0..7)
    const int f4l   = lane & 7;          // f4 slot for staging

    // compute-phase mapping
    const int f4    = tid & 7;           // float4 slot of features
    const int tg    = tid >> 3;          // 0..31
    const int tbase = tg * R_PER_T;      // 0..124

    // ---- weights -> registers, once per block (amortized 16 tiles) ----
    float wv[4][KW];
    {
        const float* wp = w + (size_t)(f0 + f4 * 4) * KW;
        #pragma unroll
        for (int c = 0; c < 4; ++c)
            #pragma unroll
            for (int k = 0; k < KW; ++k)
                wv[c][k] = wp[c * KW + k];
    }

    // ---- prologue: stage slabs 0 and 1 ----
    stage_slab(x, ring4, 0,        0,     b, f0, wv_id, rsub, f4l);
    stage_slab(x, ring4, STAGE_V4, T_OUT, b, f0, wv_id, rsub, f4l);

    // rotating float4-unit offsets: oA = slab t, oB = slab t+1, oC = dest for t+2
    int oA = 0, oB = STAGE_V4, oC = 2 * STAGE_V4;

    #pragma unroll 1
    for (int t_tile = 0; t_tile < N_TILES; ++t_tile) {
        const int t0 = t_tile * T_OUT;

        // 1. prefetch slab t+2 into oC (freed by iter t-1's post-compute barrier).
        //    Slab 16 does not exist: t=14/15 stage nothing (boundary reads masked).
        if (t_tile < N_TILES - 2)
            stage_slab(x, ring4, oC, t0 + 2 * T_OUT, b, f0, wv_id, rsub, f4l);

        // 2. counted wait (per-wave FIFO sim; 4 loads/slab, 4 stores/tile):
        //    t=0:     [s0:4][s1:4][s2:4]                   -> vmcnt(4)
        //    t=1..13: [st(t-2):4][s(t+1):4][st(t-1):4][s(t+2):4] -> vmcnt(8)
        //    t=14:    [st12:4][s15:4][st13:4]              -> vmcnt(4)
        //    t=15:    nothing new needed                   -> no wait
        if (t_tile == 0)                 WAITV(4);
        else if (t_tile < N_TILES - 2)   WAITV(8);
        else if (t_tile == N_TILES - 2)  WAITV(4);
        __builtin_amdgcn_s_barrier();

        // 3. compute: rows 0..127 from oA, rows 128..147 from head of oB
        const int oBm = oB - T_OUT * (F_TILE / 4);   // so oBm + row*8 indexes oB head
        float4 acc[R_PER_T];
        #pragma unroll
        for (int r = 0; r < R_PER_T; ++r)
            acc[r] = make_float4(0.f, 0.f, 0.f, 0.f);

        if (t_tile < N_TILES - 1) {
            #pragma unroll
            for (int s = 0; s < T_WIN; ++s) {
                const int row  = tbase + s;
                const int base = (row < T_OUT) ? oA : oBm;
                f32x4_t xv = ring4[base + row * (F_TILE / 4) + f4];  // typed: b128
                #pragma unroll
                for (int r = 0; r < R_PER_T; ++r) {
                    const int k = s - r;
                    if (k >= 0 && k < KW) {
                        acc[r].x = fmaf(xv.x, wv[0][k], acc[r].x);
                        acc[r].y = fmaf(xv.y, wv[1][k], acc[r].y);
                        acc[r].z = fmaf(xv.z, wv[2][k], acc[r].z);
                        acc[r].w = fmaf(xv.w, wv[3][k], acc[r].w);
                    }
                }
            }
        } else {
            // boundary tile: rows >= S_LEN (all oB-head reads here) masked to zero;
            // the LDS read may hit stale data, value discarded by the mask.
            #pragma unroll
            for (int s = 0; s < T_WIN; ++s) {
                const int row  = tbase + s;
                const int base = (row < T_OUT) ? oA : oBm;
                f32x4_t xv = ring4[base + row * (F_TILE / 4) + f4];
                if (t0 + row >= S_LEN) xv = (f32x4_t){0.f, 0.f, 0.f, 0.f};
                #pragma unroll
                for (int r = 0; r < R_PER_T; ++r) {
                    const int k = s - r;
                    if (k >= 0 && k < KW) {
                        acc[r].x = fmaf(xv.x, wv[0][k], acc[r].x);
                        acc[r].y = fmaf(xv.y, wv[1][k], acc[r].y);
                        acc[r].z = fmaf(xv.z, wv[2][k], acc[r].z);
                        acc[r].w = fmaf(xv.w, wv[3][k], acc[r].w);
                    }
                }
            }
        }

        // 4. all waves done reading oA/oB-head -> next iter may overwrite old oA
        __builtin_amdgcn_s_barrier();

        // 5. stores (global, don't touch LDS)
        size_t obase = ((size_t)(t0 + tbase) * BATCH + b) * NF + f0 + (f4 << 2);
        #pragma unroll
        for (int r = 0; r < R_PER_T; ++r) {
            f32x4_t v = { acc[r].x, acc[r].y, acc[r].z, acc[r].w };
            __builtin_nontemporal_store(v,
                reinterpret_cast<f32x4_t*>(&out[obase + (size_t)r * BATCH * NF]));
        }

        // 6. rotate: A <- B <- C <- A
        int tmp = oA; oA = oB; oB = oC; oC = tmp;
    }
}

extern "C" void kernel_launch(void* const* d_in, const int* in_sizes, int n_in,
                              void* d_out, int out_size, void* d_ws, size_t ws_size,
                              hipStream_t stream) {
    const float* x = (const float*)d_in[0];
    const float* w = (const float*)d_in[1];
    float* out     = (float*)d_out;

    dim3 grid(NF / F_TILE, BATCH);   // (32, 32) = 1024 blocks, 3/CU resident
    dim3 block(256);
    lookahead_dwconv_kernel<<<grid, block, 0, stream>>>(x, w, out);
}